// Round 10
// baseline (2149.697 us; speedup 1.0000x reference)
//
#include <hip/hip_runtime.h>
#include <hip/hip_bf16.h>
#include <cstdint>

typedef unsigned short u16;
typedef __attribute__((ext_vector_type(8))) u16 u16x8;
typedef __attribute__((ext_vector_type(8))) short s16x8;   // bf16 MFMA frag
typedef __attribute__((ext_vector_type(4))) float f32x4;

#define AS1(p) ((const __attribute__((address_space(1))) void*)(p))
#define AS3(p) ((__attribute__((address_space(3))) void*)(p))

__device__ __forceinline__ u16 f2bf(float f){
  union{float f; uint32_t i;} x; x.f = f;
  uint32_t r = x.i + 0x7fff + ((x.i>>16)&1);
  return (u16)(r>>16);
}

// ------------- weight transpose: in f32 [K][N] -> out bf16 [N][K] ------------
__global__ void transpose_f32_bf16(const float* __restrict__ in, u16* __restrict__ out,
                                   int K, int N){
  __shared__ u16 tile[32][33];
  const int tid = threadIdx.x;
  const int bx = blockIdx.x, by = blockIdx.y;
  const int xl = tid & 31, yl = tid >> 5;
  #pragma unroll
  for (int r = 0; r < 4; ++r){
    int y = by*32 + yl + r*8;
    tile[yl + r*8][xl] = f2bf(in[(size_t)y*N + bx*32 + xl]);
  }
  __syncthreads();
  #pragma unroll
  for (int r = 0; r < 4; ++r){
    int oy = bx*32 + yl + r*8;
    int ox = by*32 + xl;
    out[(size_t)oy*K + ox] = tile[xl][yl + r*8];
  }
}

// -------- bias1[t][h] = b1[h] + cH_t*W1[2048,h] + cS_t*W1[2049,h] (f32) ------
__global__ void build_bias1(const float* __restrict__ W1, const float* __restrict__ b1,
                            const int* __restrict__ head, const int* __restrict__ tail,
                            const int* __restrict__ sign, float* __restrict__ bias1){
  int idx = blockIdx.x*256 + threadIdx.x;
  int t = idx >> 12, h = idx & 4095;
  float cH = 0.f, cS = 0.f;
  #pragma unroll
  for (int e = 0; e < 16; ++e){
    float s = 1.f - 2.f*(float)sign[e];
    if (head[e] == t){ cH += 1.f; cS += s; }
    if (tail[e] == t){ cH -= 1.f; cS += s; }
  }
  bias1[idx] = b1[h] + cH*W1[(size_t)2048*4096 + h] + cS*W1[(size_t)2049*4096 + h];
}

// --- X1[r,0:1024] = bf16(deg_t*term[r]); X1[r,1024:2048] = bf16(sum pred) ----
__global__ void build_x1(const float* __restrict__ term, const float* __restrict__ pred,
                         const int* __restrict__ head, const int* __restrict__ tail,
                         u16* __restrict__ X1, int r0){
  int idx = blockIdx.x*256 + threadIdx.x;
  int lr = idx >> 8;
  int c8 = (idx & 255) * 8;
  int grow = r0 + lr;
  int t = grow >> 12;
  int b = grow & 4095;
  float v[8];
  if (c8 < 1024){
    int deg = 0;
    #pragma unroll
    for (int e = 0; e < 16; ++e) deg += (head[e]==t) + (tail[e]==t);
    float d = (float)deg;
    const float4* p = (const float4*)(term + (size_t)grow*1024 + c8);
    float4 lo = p[0], hi = p[1];
    v[0]=d*lo.x; v[1]=d*lo.y; v[2]=d*lo.z; v[3]=d*lo.w;
    v[4]=d*hi.x; v[5]=d*hi.y; v[6]=d*hi.z; v[7]=d*hi.w;
  } else {
    int f = c8 - 1024;
    #pragma unroll
    for (int j = 0; j < 8; ++j) v[j] = 0.f;
    #pragma unroll
    for (int e = 0; e < 16; ++e){
      int w = (head[e]==t) + (tail[e]==t);
      if (w){
        const float4* p = (const float4*)(pred + ((size_t)e<<22) + ((size_t)b<<10) + f);
        float4 lo = p[0], hi = p[1];
        float fw = (float)w;
        v[0]+=fw*lo.x; v[1]+=fw*lo.y; v[2]+=fw*lo.z; v[3]+=fw*lo.w;
        v[4]+=fw*hi.x; v[5]+=fw*hi.y; v[6]+=fw*hi.z; v[7]+=fw*hi.w;
      }
    }
  }
  u16x8 o;
  #pragma unroll
  for (int j = 0; j < 8; ++j) o[j] = f2bf(v[j]);
  *(u16x8*)(X1 + (size_t)lr*2048 + c8) = o;
}

// ====== 256x256 GEMM: A via LDS (64KB, quartered), B global->reg direct ======
// LDS-traffic cut: B bypasses LDS (loads are 64B-coalesced per quarter-wave,
// L2-resident). Per K-tile per CU, LDS drops 2684->~1630 cyc vs MFMA 2483 ->
// MFMA becomes the single binding pipe.
// A LDS = 2 slots x 4 quarter-regions Q0..Q3 (64 rows x 64 k, 8KB each, one
// global_load_lds per Q). Tile kt (slot s=kt&1): phase A reads (s,Q0/Q2),
// phase B reads (s,Q1/Q3). Stages: kt.A stages (s^1, Q1/Q3, kt+1) [last read
// kt-1.B, tile-start BAR guards]; kt.B stages (s, Q0/Q2, kt+2) [read this
// tile's phase A, mid-BAR guards]. Same-wave gload-vs-ds_read races: none,
// staged regions are never read by the staging tile's remaining phases.
// RAW (no manual vmcnt needed): all 8 B(kt) reg-loads are consumed by phase-A
// MFMAs, so the compiler's B(kt)-consumption waits drain every vmem issued
// before B(kt) -- which includes every A-stage >= 1 tile old -- before the
// mid-BAR, hence before any ds_read of those regions. Verified for both stage
// classes and the prologue (prologue uses one explicit vmcnt(2)).
// Swizzle: within each Q, physical group = logical ^ (row&7)  (round-5
// pattern, PMC-verified 0 conflicts; 16-row steps preserve row&7).
#define FENCE() asm volatile("" ::: "memory")
#define BAR()   do{ FENCE(); __builtin_amdgcn_s_barrier(); FENCE(); }while(0)

#define STAGE_Q(slot, q, kt) \
    __builtin_amdgcn_global_load_lds( \
        AS1(aStage + (size_t)(q)*64*K + ((size_t)(kt) << 6)), \
        AS3(&LDS[(slot)*16384 + (q)*4096 + tid*8]), 16, 0, 0)

// A frags for row-half rh from slot: 8 ds_read_b128 (region q = wr*2+rh)
#define LOADA(slot, rh) do{ \
    _Pragma("unroll") \
    for (int ii = 0; ii < 4; ++ii){ \
      af[ii][0] = *(const s16x8*)&LDS[(slot)*16384 + aQ + (rh)*4096 + ii*1024 + xv0]; \
      af[ii][1] = *(const s16x8*)&LDS[(slot)*16384 + aQ + (rh)*4096 + ii*1024 + xv1]; \
    } }while(0)

// B frags for K-tile kt: 8 global 16B loads (compiler-tracked vmcnt)
#define LOADB_G(kt) do{ \
    _Pragma("unroll") \
    for (int jj = 0; jj < 4; ++jj){ \
      bfr[jj][0] = *(const s16x8*)(bRow + (size_t)jj*K16 + ((size_t)(kt) << 6)); \
      bfr[jj][1] = *(const s16x8*)(bRow + (size_t)jj*K16 + ((size_t)(kt) << 6) + 32); \
    } }while(0)

// h-outer: 16 MFMA, each acc updated once per hh -> dep distance 8
#define MFMAQ(rh, ch) do{ \
    _Pragma("unroll") \
    for (int hh = 0; hh < 2; ++hh){ \
      _Pragma("unroll") \
      for (int ii = 0; ii < 4; ++ii){ \
        _Pragma("unroll") \
        for (int jj = 0; jj < 2; ++jj){ \
          acc[(rh)*4+ii][(ch)*2+jj] = __builtin_amdgcn_mfma_f32_16x16x32_bf16(af[ii][hh], bfr[(ch)*2+jj][hh], acc[(rh)*4+ii][(ch)*2+jj], 0,0,0); \
        } } } }while(0)

template<int MODE>
__launch_bounds__(512, 2)
__global__ void gemm256(const u16* __restrict__ A, const u16* __restrict__ Bt,
                        void* __restrict__ Cv, int N, int K, int r0,
                        const float* __restrict__ bias_mat,
                        const float* __restrict__ bias_vec,
                        const float* __restrict__ resid){
  __shared__ u16 LDS[32768];   // 64 KiB: 2 slots x 4 Q x (64 rows x 64 u16)
  const int tid = threadIdx.x;
  const int lane = tid & 63;
  const int wid = tid >> 6;
  const int wr = wid >> 2, wc = wid & 3;
  const int frow = lane & 15, fgrp = lane >> 4;

  // T1: bijective XCD swizzle
  int nwg = gridDim.x * gridDim.y;
  int orig = blockIdx.y * gridDim.x + blockIdx.x;
  int id = orig;
  if ((nwg & 7) == 0){ int cpx = nwg >> 3; id = (orig & 7) * cpx + (orig >> 3); }
  const int bx = id % gridDim.x, by = id / gridDim.x;
  const int row0 = by * 256, col0 = bx * 256;

  // A stage: pre-swizzled global source, linear LDS dest (one gload per Q)
  const u16* aStage = A + (size_t)row0 * K + (size_t)(tid >> 3) * K
                        + (((tid & 7) ^ ((tid >> 3) & 7)) << 3);
  // B: per-wave row base (col0 + wc*64 + frow), k-base fgrp*8
  const u16* bRow = Bt + (size_t)(col0 + wc*64 + frow) * K + fgrp*8;
  const size_t K16 = (size_t)K * 16;

  // A fragment read offsets (u16), de-swizzled
  const int xv0 = ((fgrp)     ^ (frow & 7)) << 3;
  const int xv1 = ((4 + fgrp) ^ (frow & 7)) << 3;
  const int aQ = wr * 8192 + frow * 64;   // wave's Q-pair base + row-in-region

  f32x4 acc[8][4];
  #pragma unroll
  for (int i = 0; i < 8; ++i)
    #pragma unroll
    for (int j = 0; j < 4; ++j) acc[i][j] = (f32x4){0.f,0.f,0.f,0.f};
  s16x8 af[4][2], bfr[4][2];

  const int NT = K >> 6;       // K-tiles (BK=64); even, >= 16 for all our Ks
  const int NI = NT >> 1;

  // prologue: tile0 all 4 quarters, tile1 Q0/Q2. vmcnt(2) -> tile0 landed.
  STAGE_Q(0,0,0); STAGE_Q(0,2,0); STAGE_Q(0,1,0); STAGE_Q(0,3,0);
  STAGE_Q(1,0,1); STAGE_Q(1,2,1);
  asm volatile("s_waitcnt vmcnt(2)" ::: "memory");
  BAR();

  for (int i = 0; i < NI; ++i){
    const int kt0 = 2*i, kt1 = 2*i + 1;
    // ================= tile kt0 (slot 0) =================
    // phase A: B(kt0) (all consumed this phase) ; stage (1,Q1/Q3,kt1)
    LOADB_G(kt0);
    STAGE_Q(1,1,kt1); STAGE_Q(1,3,kt1);
    LOADA(0,0);
    MFMAQ(0,0); MFMAQ(0,1);
    BAR();
    // phase B: stage (0,Q0/Q2,kt0+2); reads (0,Q1/Q3)
    if (kt0 + 2 < NT){ STAGE_Q(0,0,kt0+2); STAGE_Q(0,2,kt0+2); }
    LOADA(0,1);
    MFMAQ(1,0); MFMAQ(1,1);
    BAR();
    // ================= tile kt1 (slot 1) =================
    // phase A: B(kt1); stage (0,Q1/Q3,kt1+1)
    LOADB_G(kt1);
    if (kt1 + 1 < NT){ STAGE_Q(0,1,kt1+1); STAGE_Q(0,3,kt1+1); }
    LOADA(1,0);
    MFMAQ(0,0); MFMAQ(0,1);
    BAR();
    // phase B: stage (1,Q0/Q2,kt1+2); reads (1,Q1/Q3)
    if (kt1 + 2 < NT){ STAGE_Q(1,0,kt1+2); STAGE_Q(1,2,kt1+2); }
    LOADA(1,1);
    MFMAQ(1,0); MFMAQ(1,1);
    BAR();
  }

  // epilogue: C/D layout col=lane&15, row=(lane>>4)*4+reg
  #pragma unroll
  for (int i2 = 0; i2 < 8; ++i2){
    #pragma unroll
    for (int j2 = 0; j2 < 4; ++j2){
      #pragma unroll
      for (int r = 0; r < 4; ++r){
        int lrow = row0 + wr*128 + i2*16 + fgrp*4 + r;
        int col  = col0 + wc*64 + j2*16 + frow;
        float v = acc[i2][j2][r];
        if (MODE == 0){
          int grow = r0 + lrow;
          v += bias_mat[(size_t)(grow >> 12)*N + col];
          v = fmaxf(v, 0.f);
          ((u16*)Cv)[(size_t)lrow*N + col] = f2bf(v);
        } else if (MODE == 1){
          int grow = r0 + lrow;
          v += bias_vec[col] + 0.1f*resid[(size_t)grow*1024 + col];
          ((u16*)Cv)[(size_t)lrow*N + col] = f2bf(v);
        } else if (MODE == 2){
          v += bias_vec[col];
          v = fmaxf(v, 0.f);
          ((u16*)Cv)[(size_t)lrow*N + col] = f2bf(v);
        } else {
          v += bias_vec[col];
          ((float*)Cv)[(size_t)lrow*N + col] = v;
        }
      }
    }
  }
}

extern "C" void kernel_launch(void* const* d_in, const int* in_sizes, int n_in,
                              void* d_out, int out_size, void* d_ws, size_t ws_size,
                              hipStream_t stream){
  const float* term = (const float*)d_in[0];
  const float* pred = (const float*)d_in[1];
  const float* W1   = (const float*)d_in[2];
  const float* b1   = (const float*)d_in[3];
  const float* W2   = (const float*)d_in[4];
  const float* b2   = (const float*)d_in[5];
  const float* M1   = (const float*)d_in[6];
  const float* mb1  = (const float*)d_in[7];
  const float* M2   = (const float*)d_in[8];
  const float* mb2  = (const float*)d_in[9];
  const int* head = (const int*)d_in[10];
  const int* tail = (const int*)d_in[11];
  const int* sign = (const int*)d_in[12];
  float* out = (float*)d_out;

  char* ws = (char*)d_ws;
  u16* W1T = (u16*)ws;  ws += (size_t)4096*2048*2;
  u16* W2T = (u16*)ws;  ws += (size_t)1024*4096*2;
  u16* M1T = (u16*)ws;  ws += (size_t)4096*1024*2;
  u16* M2T = (u16*)ws;  ws += (size_t)1024*4096*2;
  float* bias1 = (float*)ws; ws += (size_t)8*4096*4;
  size_t used = (size_t)(ws - (char*)d_ws);

  int R = 32768;  // rows per chunk (multiple of 256)
  while (R > 256 && used + (size_t)R*12288 > ws_size) R >>= 1;
  u16* bufA = (u16*)ws;
  u16* bufB = (u16*)(ws + (size_t)R*2048*2);

  transpose_f32_bf16<<<dim3(4096/32, 2048/32), 256, 0, stream>>>(W1, W1T, 2048, 4096);
  transpose_f32_bf16<<<dim3(1024/32, 4096/32), 256, 0, stream>>>(W2, W2T, 4096, 1024);
  transpose_f32_bf16<<<dim3(4096/32, 1024/32), 256, 0, stream>>>(M1, M1T, 1024, 4096);
  transpose_f32_bf16<<<dim3(1024/32, 4096/32), 256, 0, stream>>>(M2, M2T, 4096, 1024);
  build_bias1<<<dim3(8*4096/256), 256, 0, stream>>>(W1, b1, head, tail, sign, bias1);

  for (int r0 = 0; r0 < 32768; r0 += R){
    build_x1<<<dim3(R), 256, 0, stream>>>(term, pred, head, tail, bufA, r0);
    gemm256<0><<<dim3(4096/256, R/256), 512, 0, stream>>>(bufA, W1T, bufB, 4096, 2048, r0, bias1, nullptr, nullptr);
    gemm256<1><<<dim3(1024/256, R/256), 512, 0, stream>>>(bufB, W2T, bufA, 1024, 4096, r0, nullptr, b2, term);
    gemm256<2><<<dim3(4096/256, R/256), 512, 0, stream>>>(bufA, M1T, bufB, 4096, 1024, r0, nullptr, mb1, nullptr);
    gemm256<3><<<dim3(1024/256, R/256), 512, 0, stream>>>(bufB, M2T, out + (size_t)r0*1024, 1024, 4096, r0, nullptr, mb2, nullptr);
  }
}

// Round 12
// 1349.909 us; speedup vs baseline: 1.5925x; 1.5925x over previous
//
#include <hip/hip_runtime.h>
#include <hip/hip_bf16.h>
#include <cstdint>

typedef unsigned short u16;
typedef __attribute__((ext_vector_type(8))) u16 u16x8;
typedef __attribute__((ext_vector_type(8))) short s16x8;   // bf16 MFMA frag
typedef __attribute__((ext_vector_type(4))) float f32x4;

#define AS1(p) ((const __attribute__((address_space(1))) void*)(p))
#define AS3(p) ((__attribute__((address_space(3))) void*)(p))

__device__ __forceinline__ u16 f2bf(float f){
  union{float f; uint32_t i;} x; x.f = f;
  uint32_t r = x.i + 0x7fff + ((x.i>>16)&1);
  return (u16)(r>>16);
}

// ------------- weight transpose: in f32 [K][N] -> out bf16 [N][K] ------------
__global__ void transpose_f32_bf16(const float* __restrict__ in, u16* __restrict__ out,
                                   int K, int N){
  __shared__ u16 tile[32][33];
  const int tid = threadIdx.x;
  const int bx = blockIdx.x, by = blockIdx.y;
  const int xl = tid & 31, yl = tid >> 5;
  #pragma unroll
  for (int r = 0; r < 4; ++r){
    int y = by*32 + yl + r*8;
    tile[yl + r*8][xl] = f2bf(in[(size_t)y*N + bx*32 + xl]);
  }
  __syncthreads();
  #pragma unroll
  for (int r = 0; r < 4; ++r){
    int oy = bx*32 + yl + r*8;
    int ox = by*32 + xl;
    out[(size_t)oy*K + ox] = tile[xl][yl + r*8];
  }
}

// -------- bias1[t][h] = b1[h] + cH_t*W1[2048,h] + cS_t*W1[2049,h] (f32) ------
__global__ void build_bias1(const float* __restrict__ W1, const float* __restrict__ b1,
                            const int* __restrict__ head, const int* __restrict__ tail,
                            const int* __restrict__ sign, float* __restrict__ bias1){
  int idx = blockIdx.x*256 + threadIdx.x;
  int t = idx >> 12, h = idx & 4095;
  float cH = 0.f, cS = 0.f;
  #pragma unroll
  for (int e = 0; e < 16; ++e){
    float s = 1.f - 2.f*(float)sign[e];
    if (head[e] == t){ cH += 1.f; cS += s; }
    if (tail[e] == t){ cH -= 1.f; cS += s; }
  }
  bias1[idx] = b1[h] + cH*W1[(size_t)2048*4096 + h] + cS*W1[(size_t)2049*4096 + h];
}

// --- X1[r,0:1024] = bf16(deg_t*term[r]); X1[r,1024:2048] = bf16(sum pred) ----
__global__ void build_x1(const float* __restrict__ term, const float* __restrict__ pred,
                         const int* __restrict__ head, const int* __restrict__ tail,
                         u16* __restrict__ X1, int r0){
  int idx = blockIdx.x*256 + threadIdx.x;
  int lr = idx >> 8;
  int c8 = (idx & 255) * 8;
  int grow = r0 + lr;
  int t = grow >> 12;
  int b = grow & 4095;
  float v[8];
  if (c8 < 1024){
    int deg = 0;
    #pragma unroll
    for (int e = 0; e < 16; ++e) deg += (head[e]==t) + (tail[e]==t);
    float d = (float)deg;
    const float4* p = (const float4*)(term + (size_t)grow*1024 + c8);
    float4 lo = p[0], hi = p[1];
    v[0]=d*lo.x; v[1]=d*lo.y; v[2]=d*lo.z; v[3]=d*lo.w;
    v[4]=d*hi.x; v[5]=d*hi.y; v[6]=d*hi.z; v[7]=d*hi.w;
  } else {
    int f = c8 - 1024;
    #pragma unroll
    for (int j = 0; j < 8; ++j) v[j] = 0.f;
    #pragma unroll
    for (int e = 0; e < 16; ++e){
      int w = (head[e]==t) + (tail[e]==t);
      if (w){
        const float4* p = (const float4*)(pred + ((size_t)e<<22) + ((size_t)b<<10) + f);
        float4 lo = p[0], hi = p[1];
        float fw = (float)w;
        v[0]+=fw*lo.x; v[1]+=fw*lo.y; v[2]+=fw*lo.z; v[3]+=fw*lo.w;
        v[4]+=fw*hi.x; v[5]+=fw*hi.y; v[6]+=fw*hi.z; v[7]+=fw*hi.w;
      }
    }
  }
  u16x8 o;
  #pragma unroll
  for (int j = 0; j < 8; ++j) o[j] = f2bf(v[j]);
  *(u16x8*)(X1 + (size_t)lr*2048 + c8) = o;
}

// ====== 256x256 GEMM, slice-cycled frags, A 3-slot / B 2-slot LDS (160KB) ====
// Frag buffers: S0,S1 (A rows 0-63 / 64-127 of wave half), T0,T1 (B j01/j23).
// Per tile kt (A-slot kt%3, B-slot kt&1), 4 regions, group order
// (S0,T0),(S1,T0),(S0,T1),(S1,T1) -- each buffer reloaded 1-2 regions after
// its last consuming MFMA cluster (no tight register WAR, the r5-r9
// serializer suspect), and single T0/T1 suffice (96 frag VGPRs):
//   Ra: MG(S0,T0);           load S1<-A(kt)
//   Rb: MG(S1,T0); load T1<-B(kt) j23; STAGE_A(kt+2); VM4   <- VM before BAR!
//   Rc: MG(S0,T1); load T0<-B(kt+1) j01
//   Rd: MG(S1,T1); load S0<-A(kt+1);   STAGE_B(kt+2)
// VM4@Rb drains {A(kt+1), B(kt+1)} (queue 12->4), leaves A(kt+2) in flight;
// cross-wave safe: every LDS read is preceded by all-waves VM4 + >=1 barrier.
// WAR: A-slot restaged 4 barriers after its last read-consumption; B-slot
// restaged 1 barrier after its last reads' consuming region (consumption-
// before-barrier argument). In-flight never drains to 0 mid-loop.
// Tail: kc clamp re-stages NT-1 into dead slots (valid addrs, never read).
#define FENCE() asm volatile("" ::: "memory")
#define BAR()   do{ FENCE(); __builtin_amdgcn_s_barrier(); FENCE(); }while(0)
#define VM0()   asm volatile("s_waitcnt vmcnt(0)" ::: "memory")
#define VM4()   asm volatile("s_waitcnt vmcnt(4)" ::: "memory")

// A slot a (0..2): u16 base a*16384; row r (0-255) at r*64, swizzled groups
#define STAGE_A(slot, half, kt) do{ \
    const u16* _s = aStage + (size_t)(half)*halfStride + ((size_t)(kt) << 6); \
    u16* _d = &LDS[(slot)*16384 + (half)*8192 + tid*8]; \
    __builtin_amdgcn_global_load_lds(AS1(_s), AS3(_d), 16, 0, 0); \
    __builtin_amdgcn_global_load_lds(AS1(_s + q2s), AS3(_d + 4096), 16, 0, 0); \
  }while(0)
// B slot b (0..1): u16 base 49152 + b*16384; col c at c*64
#define STAGE_B(slot, half, kt) do{ \
    const u16* _s = bStage + (size_t)(half)*halfStride + ((size_t)(kt) << 6); \
    u16* _d = &LDS[49152 + (slot)*16384 + (half)*8192 + tid*8]; \
    __builtin_amdgcn_global_load_lds(AS1(_s), AS3(_d), 16, 0, 0); \
    __builtin_amdgcn_global_load_lds(AS1(_s + q2s), AS3(_d + 4096), 16, 0, 0); \
  }while(0)

// A slice sh (0/1) from A-slot a: 8 ds_read_b128
#define LOADS(Sv, a, sh) do{ \
    _Pragma("unroll") \
    for (int hh = 0; hh < 2; ++hh){ \
      _Pragma("unroll") \
      for (int ii = 0; ii < 4; ++ii){ \
        Sv[ii][hh] = *(const s16x8*)&LDS[(a)*16384 + aB + (sh)*4096 + ii*1024 + (hh ? xv1 : xv0)]; \
      } } }while(0)

// B slice th (0: j01, 1: j23) from B-slot b: 4 ds_read_b128
#define LOADT(Tv, b, th) do{ \
    _Pragma("unroll") \
    for (int hh = 0; hh < 2; ++hh){ \
      _Pragma("unroll") \
      for (int jj = 0; jj < 2; ++jj){ \
        Tv[jj][hh] = *(const s16x8*)&LDS[49152 + (b)*16384 + bB + ((th)*2+jj)*1024 + (hh ? xv1 : xv0)]; \
      } } }while(0)

// 16 MFMA, hh-outer (each acc touched at dep distance 8)
#define MG(Sv, Tv, sh, th) do{ \
    _Pragma("unroll") \
    for (int hh = 0; hh < 2; ++hh){ \
      _Pragma("unroll") \
      for (int ii = 0; ii < 4; ++ii){ \
        _Pragma("unroll") \
        for (int jj = 0; jj < 2; ++jj){ \
          acc[(sh)*4+ii][(th)*2+jj] = __builtin_amdgcn_mfma_f32_16x16x32_bf16(Sv[ii][hh], Tv[jj][hh], acc[(sh)*4+ii][(th)*2+jj], 0,0,0); \
        } } } }while(0)

template<int MODE>
__launch_bounds__(512, 1)
__global__ void gemm256(const u16* __restrict__ A, const u16* __restrict__ Bt,
                        void* __restrict__ Cv, int N, int K, int r0,
                        const float* __restrict__ bias_mat,
                        const float* __restrict__ bias_vec,
                        const float* __restrict__ resid){
  __shared__ u16 LDS[81920];   // 160 KiB: A 3x32KB @0, B 2x32KB @49152
  const int tid = threadIdx.x;
  const int lane = tid & 63;
  const int wid = tid >> 6;
  const int wr = wid >> 2, wc = wid & 3;
  const int frow = lane & 15, fgrp = lane >> 4;

  // T1: bijective XCD swizzle
  int nwg = gridDim.x * gridDim.y;
  int orig = blockIdx.y * gridDim.x + blockIdx.x;
  int id = orig;
  if ((nwg & 7) == 0){ int cpx = nwg >> 3; id = (orig & 7) * cpx + (orig >> 3); }
  const int bx = id % gridDim.x, by = id / gridDim.x;
  const int row0 = by * 256, col0 = bx * 256;

  // stage source bases (pre-swizzled global source, linear LDS dest):
  // dest row r = tid>>3 (+64 for 2nd gload, +128*half); slot s=tid&7 holds
  // global group s ^ (r&7); key(r)==key(r+64) so one source offset serves both.
  const size_t rowK = (size_t)(tid >> 3) * K;
  const int sg8 = (((tid & 7) ^ ((tid >> 3) & 7)) << 3);
  const u16* aStage = A  + (size_t)row0 * K + rowK + sg8;
  const u16* bStage = Bt + (size_t)col0 * K + rowK + sg8;
  const size_t halfStride = (size_t)128 * K;
  const size_t q2s = (size_t)64 * K;

  // fragment read offsets (u16), de-swizzled (r5-verified, PMC 0 conflicts)
  const int xv0 = ((fgrp)     ^ (frow & 7)) << 3;
  const int xv1 = ((4 + fgrp) ^ (frow & 7)) << 3;
  const int aB = wr * 8192 + frow * 64;   // + sh*4096 + ii*1024
  const int bB = wc * 4096 + frow * 64;   // + (th*2+jj)*1024

  f32x4 acc[8][4];
  #pragma unroll
  for (int i = 0; i < 8; ++i)
    #pragma unroll
    for (int j = 0; j < 4; ++j) acc[i][j] = (f32x4){0.f,0.f,0.f,0.f};
  s16x8 S0[4][2], S1[4][2], T0[2][2], T1[2][2];

  const int NT = K >> 6;       // K-tiles (BK=64); >= 16 for all our Ks

  // prologue: A(0)->s0, A(1)->s1, B(0)->b0, B(1)->b1; drain ALL before BAR
  STAGE_A(0,0,0); STAGE_A(0,1,0); STAGE_A(1,0,1); STAGE_A(1,1,1);
  STAGE_B(0,0,0); STAGE_B(0,1,0); STAGE_B(1,0,1); STAGE_B(1,1,1);
  VM0(); BAR();
  LOADS(S0, 0, 0);            // S0 <- A(0) rows 0-63
  LOADT(T0, 0, 0);            // T0 <- B(0) j01

  int s0i = 0, s1i = 1, s2i = 2;   // A slots of kt, kt+1, kt+2
  int bS = 0;                      // B slot of kt
  for (int kt = 0; kt < NT; ++kt){
    const int kc = (kt + 2 < NT) ? kt + 2 : NT - 1;  // clamp: dead-slot write
    // Ra: MG(S0,T0); load S1 <- A(kt) rows 64-127
    BAR();
    MG(S0, T0, 0, 0);
    LOADS(S1, s0i, 1);
    // Rb: MG(S1,T0); load T1 <- B(kt) j23; stage A(kt+2); VM4 BEFORE barrier
    BAR();
    MG(S1, T0, 1, 0);
    LOADT(T1, bS, 1);
    STAGE_A(s2i, 0, kc); STAGE_A(s2i, 1, kc);
    VM4();
    // Rc: MG(S0,T1); load T0 <- B(kt+1) j01 (drained by VM4 + barrier)
    BAR();
    MG(S0, T1, 0, 1);
    LOADT(T0, bS ^ 1, 0);
    // Rd: MG(S1,T1); load S0 <- A(kt+1) rows 0-63; stage B(kt+2)
    BAR();
    MG(S1, T1, 1, 1);
    LOADS(S0, s1i, 0);
    STAGE_B(bS, 0, kc); STAGE_B(bS, 1, kc);
    // rotate slots
    int tsw = s0i; s0i = s1i; s1i = s2i; s2i = tsw;
    bS ^= 1;
  }
  VM0();   // drain trailing stages before workgroup end

  // epilogue: C/D layout col=lane&15, row=(lane>>4)*4+reg
  #pragma unroll
  for (int i2 = 0; i2 < 8; ++i2){
    #pragma unroll
    for (int j2 = 0; j2 < 4; ++j2){
      #pragma unroll
      for (int r = 0; r < 4; ++r){
        int lrow = row0 + wr*128 + i2*16 + fgrp*4 + r;
        int col  = col0 + wc*64 + j2*16 + frow;
        float v = acc[i2][j2][r];
        if (MODE == 0){
          int grow = r0 + lrow;
          v += bias_mat[(size_t)(grow >> 12)*N + col];
          v = fmaxf(v, 0.f);
          ((u16*)Cv)[(size_t)lrow*N + col] = f2bf(v);
        } else if (MODE == 1){
          int grow = r0 + lrow;
          v += bias_vec[col] + 0.1f*resid[(size_t)grow*1024 + col];
          ((u16*)Cv)[(size_t)lrow*N + col] = f2bf(v);
        } else if (MODE == 2){
          v += bias_vec[col];
          v = fmaxf(v, 0.f);
          ((u16*)Cv)[(size_t)lrow*N + col] = f2bf(v);
        } else {
          v += bias_vec[col];
          ((float*)Cv)[(size_t)lrow*N + col] = v;
        }
      }
    }
  }
}

extern "C" void kernel_launch(void* const* d_in, const int* in_sizes, int n_in,
                              void* d_out, int out_size, void* d_ws, size_t ws_size,
                              hipStream_t stream){
  const float* term = (const float*)d_in[0];
  const float* pred = (const float*)d_in[1];
  const float* W1   = (const float*)d_in[2];
  const float* b1   = (const float*)d_in[3];
  const float* W2   = (const float*)d_in[4];
  const float* b2   = (const float*)d_in[5];
  const float* M1   = (const float*)d_in[6];
  const float* mb1  = (const float*)d_in[7];
  const float* M2   = (const float*)d_in[8];
  const float* mb2  = (const float*)d_in[9];
  const int* head = (const int*)d_in[10];
  const int* tail = (const int*)d_in[11];
  const int* sign = (const int*)d_in[12];
  float* out = (float*)d_out;

  char* ws = (char*)d_ws;
  u16* W1T = (u16*)ws;  ws += (size_t)4096*2048*2;
  u16* W2T = (u16*)ws;  ws += (size_t)1024*4096*2;
  u16* M1T = (u16*)ws;  ws += (size_t)4096*1024*2;
  u16* M2T = (u16*)ws;  ws += (size_t)1024*4096*2;
  float* bias1 = (float*)ws; ws += (size_t)8*4096*4;
  size_t used = (size_t)(ws - (char*)d_ws);

  int R = 32768;  // rows per chunk (multiple of 256)
  while (R > 256 && used + (size_t)R*12288 > ws_size) R >>= 1;
  u16* bufA = (u16*)ws;
  u16* bufB = (u16*)(ws + (size_t)R*2048*2);

  transpose_f32_bf16<<<dim3(4096/32, 2048/32), 256, 0, stream>>>(W1, W1T, 2048, 4096);
  transpose_f32_bf16<<<dim3(1024/32, 4096/32), 256, 0, stream>>>(W2, W2T, 4096, 1024);
  transpose_f32_bf16<<<dim3(4096/32, 1024/32), 256, 0, stream>>>(M1, M1T, 1024, 4096);
  transpose_f32_bf16<<<dim3(1024/32, 4096/32), 256, 0, stream>>>(M2, M2T, 4096, 1024);
  build_bias1<<<dim3(8*4096/256), 256, 0, stream>>>(W1, b1, head, tail, sign, bias1);

  for (int r0 = 0; r0 < 32768; r0 += R){
    build_x1<<<dim3(R), 256, 0, stream>>>(term, pred, head, tail, bufA, r0);
    gemm256<0><<<dim3(4096/256, R/256), 512, 0, stream>>>(bufA, W1T, bufB, 4096, 2048, r0, bias1, nullptr, nullptr);
    gemm256<1><<<dim3(1024/256, R/256), 512, 0, stream>>>(bufB, W2T, bufA, 1024, 4096, r0, nullptr, b2, term);
    gemm256<2><<<dim3(4096/256, R/256), 512, 0, stream>>>(bufA, M1T, bufB, 4096, 1024, r0, nullptr, mb1, nullptr);
    gemm256<3><<<dim3(1024/256, R/256), 512, 0, stream>>>(bufB, M2T, out + (size_t)r0*1024, 1024, 4096, r0, nullptr, mb2, nullptr);
  }
}